// Round 3
// baseline (235.211 us; speedup 1.0000x reference)
//
#include <hip/hip_runtime.h>
#include <stdint.h>

#define D_MODEL 1024
#define NHEAD 16
#define DK 64
#define BATCH 2
#define SEQ 2048
#define NROW 4096  // BATCH*SEQ

typedef __attribute__((ext_vector_type(8))) _Float16 f16x8;
typedef __attribute__((ext_vector_type(4))) float f32x4;

__device__ __forceinline__ uint16_t f2h(float x) {
    _Float16 h = (_Float16)x;
    union { _Float16 h; uint16_t u; } cv;
    cv.h = h;
    return cv.u;
}

__device__ __forceinline__ float fexp2(float x) {
#if __has_builtin(__builtin_amdgcn_exp2f)
    return __builtin_amdgcn_exp2f(x);
#else
    return exp2f(x);
#endif
}

// async global->LDS DMA, 16B per lane, LDS dst = wave-uniform base + lane*16
__device__ __forceinline__ void lds_dma16(const uint16_t* g, uint16_t* l) {
    __builtin_amdgcn_global_load_lds((const __attribute__((address_space(1))) void*)g,
                                     (__attribute__((address_space(3))) void*)l,
                                     16, 0, 0);
}

// ---------- merged f32->f16 conversion (y=0..6) + mask->lens (y=7) ----------
struct CvtArgs {
    const float* src[7];
    uint16_t* dst[7];
    int n4[7];
};
__global__ void cvt_all_kernel(CvtArgs a, const int* __restrict__ mask, int* __restrict__ lens) {
    int t = blockIdx.y;
    if (t == 7) {
        if (blockIdx.x != 0) return;
        __shared__ int red[256];
        int tid = threadIdx.x;
        int mx = 0;
        for (int i = tid; i < 1024; i += 256) { int v = mask[i]; if (v > mx) mx = v; }
        red[tid] = mx; __syncthreads();
        for (int s = 128; s > 0; s >>= 1) { if (tid < s) { if (red[tid+s] > red[tid]) red[tid] = red[tid+s]; } __syncthreads(); }
        int bytemode = (red[0] > 1);
        __syncthreads();
        const unsigned char* mb = (const unsigned char*)mask;
        for (int b = 0; b < BATCH; ++b) {
            int cnt = 0;
            for (int tt = tid; tt < SEQ; tt += 256) {
                int v = bytemode ? (int)mb[b*SEQ + tt] : mask[b*SEQ + tt];
                cnt += (v != 0) ? 1 : 0;
            }
            red[tid] = cnt; __syncthreads();
            for (int s = 128; s > 0; s >>= 1) { if (tid < s) red[tid] += red[tid+s]; __syncthreads(); }
            if (tid == 0) lens[b] = red[0];
            __syncthreads();
        }
        return;
    }
    const float* src = a.src[t];
    uint16_t* dst = a.dst[t];
    int n4 = a.n4[t];
    int i = blockIdx.x * blockDim.x + threadIdx.x;
    int stride = gridDim.x * blockDim.x;
    for (; i < n4; i += stride) {
        float4 v = ((const float4*)src)[i];
        ushort4 o;
        o.x = f2h(v.x); o.y = f2h(v.y); o.z = f2h(v.z); o.w = f2h(v.w);
        ((ushort4*)dst)[i] = o;
    }
}

// ---------- 128x128 NT GEMM core, BK=64, global_load_lds + XOR-swizzled LDS ----------
__device__ __forceinline__ void gemm_tile_core(const uint16_t* __restrict__ A,
                                               const uint16_t* __restrict__ W,
                                               int bx, int by,
                                               uint16_t* As, uint16_t* Bs,
                                               f32x4 (&acc)[4][4]) {
    const f32x4 fzero = {0.f, 0.f, 0.f, 0.f};
    int tid = threadIdx.x;
    int lane = tid & 63, wave = tid >> 6;
    int wm = wave >> 1, wn = wave & 1;
    int l15 = lane & 15, quad = lane >> 4;
    int rl = lane >> 3, cb8 = lane & 7;  // DMA: 1KB chunk = 8 rows x 128B
#pragma unroll
    for (int mi = 0; mi < 4; mi++)
#pragma unroll
        for (int ni = 0; ni < 4; ni++) acc[mi][ni] = fzero;

    for (int k0 = 0; k0 < D_MODEL; k0 += 64) {
        __syncthreads();
#pragma unroll
        for (int i = 0; i < 4; ++i) {
            int d8 = wave * 4 + i;
            int row = d8 * 8 + rl;
            int cbg = cb8 ^ rl;
            lds_dma16(A + (size_t)(bx * 128 + row) * D_MODEL + k0 + cbg * 8, As + d8 * 512);
            lds_dma16(W + (size_t)(by * 128 + row) * D_MODEL + k0 + cbg * 8, Bs + d8 * 512);
        }
        __syncthreads();
#pragma unroll
        for (int ks = 0; ks < 2; ks++) {
            f16x8 af[4], bf[4];
#pragma unroll
            for (int mi = 0; mi < 4; mi++) {
                int row = wm * 64 + mi * 16 + l15;
                af[mi] = *(const f16x8*)(As + row * 64 + (((ks * 4 + quad) ^ (row & 7)) * 8));
            }
#pragma unroll
            for (int ni = 0; ni < 4; ni++) {
                int row = wn * 64 + ni * 16 + l15;
                bf[ni] = *(const f16x8*)(Bs + row * 64 + (((ks * 4 + quad) ^ (row & 7)) * 8));
            }
#pragma unroll
            for (int mi = 0; mi < 4; mi++)
#pragma unroll
                for (int ni = 0; ni < 4; ni++)
                    acc[mi][ni] = __builtin_amdgcn_mfma_f32_16x16x32_f16(af[mi], bf[ni], acc[mi][ni], 0, 0, 0);
        }
    }
}

// ---------- QKV projection; V goes through LDS transpose (aliased) ----------
#define TS_STRIDE 136  // u16; 272B rows -> 16B aligned, odd-word bank spread
__global__ __launch_bounds__(256, 3) void qkv_kernel(
    const uint16_t* __restrict__ qb, const uint16_t* __restrict__ kb, const uint16_t* __restrict__ vb,
    const uint16_t* __restrict__ wq, const uint16_t* __restrict__ wk, const uint16_t* __restrict__ wv,
    const float* __restrict__ bq, const float* __restrict__ bk, const float* __restrict__ bv,
    uint16_t* __restrict__ Qh, uint16_t* __restrict__ Kh, uint16_t* __restrict__ Vth) {
    __shared__ uint16_t smem[TS_STRIDE * 128];  // 34816B >= As+Bs (32KB) or Ts
    uint16_t* As = smem;
    uint16_t* Bs = smem + 128 * 64;
    int v = blockIdx.z;
    const uint16_t* A = (v == 0) ? qb : ((v == 1) ? kb : vb);
    const uint16_t* W = (v == 0) ? wq : ((v == 1) ? wk : wv);
    const float* bias = (v == 0) ? bq : ((v == 1) ? bk : bv);
    f32x4 acc[4][4];
    gemm_tile_core(A, W, blockIdx.x, blockIdx.y, As, Bs, acc);

    int tid = threadIdx.x, lane = tid & 63, wave = tid >> 6;
    int wm = wave >> 1, wn = wave & 1, l15 = lane & 15, quad = lane >> 4;
    // Q pre-scale folds 1/sqrt(dk) AND log2(e) so attention uses raw exp2.
    const float QSCALE = 0.125f * 1.44269504088896f;

    if (v == 2) {
        __syncthreads();  // all waves done reading As/Bs before aliasing as Ts
        uint16_t* Ts = smem;
#pragma unroll
        for (int mi = 0; mi < 4; mi++) {
#pragma unroll
            for (int ni = 0; ni < 4; ni++) {
                int col = wn * 64 + ni * 16 + l15;
                float bcol = bias[blockIdx.y * 128 + col];
#pragma unroll
                for (int r = 0; r < 4; r++) {
                    int tl = wm * 64 + mi * 16 + quad * 4 + r;
                    Ts[col * TS_STRIDE + tl] = f2h(acc[mi][ni][r] + bcol);
                }
            }
        }
        __syncthreads();
        int col = tid >> 1, th = (tid & 1) << 6;
        int gcol = blockIdx.y * 128 + col;
        int h = gcol >> 6, d = gcol & 63;
        int grow0 = blockIdx.x * 128;
        int b = grow0 >> 11, t = (grow0 & (SEQ - 1)) + th;
        size_t base = (((size_t)(b * NHEAD + h) << 6) + d) * SEQ + t;
#pragma unroll
        for (int j = 0; j < 8; j++)
            *(uint4*)(Vth + base + j * 8) = *(const uint4*)(Ts + col * TS_STRIDE + th + j * 8);
        return;
    }

#pragma unroll
    for (int mi = 0; mi < 4; mi++) {
#pragma unroll
        for (int ni = 0; ni < 4; ni++) {
            int gcol = blockIdx.y * 128 + wn * 64 + ni * 16 + l15;
            float bcol = bias[gcol];
            int h = gcol >> 6, d = gcol & 63;
#pragma unroll
            for (int r = 0; r < 4; r++) {
                int grow = blockIdx.x * 128 + wm * 64 + mi * 16 + quad * 4 + r;
                int b = grow >> 11, t = grow & (SEQ - 1);
                float val = acc[mi][ni][r] + bcol;
                size_t bh = (size_t)(b * NHEAD + h);
                if (v == 0) Qh[(bh * SEQ + t) * 64 + d] = f2h(val * QSCALE);
                else        Kh[(bh * SEQ + t) * 64 + d] = f2h(val);
            }
        }
    }
}

// ---------- output projection ----------
__global__ __launch_bounds__(256, 3) void outproj_kernel(
    const uint16_t* __restrict__ attn, const uint16_t* __restrict__ wo,
    const float* __restrict__ bo, float* __restrict__ out) {
    __shared__ uint16_t As[128 * 64], Bs[128 * 64];
    f32x4 acc[4][4];
    gemm_tile_core(attn, wo, blockIdx.x, blockIdx.y, As, Bs, acc);
    int tid = threadIdx.x, lane = tid & 63, wave = tid >> 6;
    int wm = wave >> 1, wn = wave & 1, l15 = lane & 15, quad = lane >> 4;
#pragma unroll
    for (int mi = 0; mi < 4; mi++) {
#pragma unroll
        for (int ni = 0; ni < 4; ni++) {
            int gcol = blockIdx.y * 128 + wn * 64 + ni * 16 + l15;
            float bcol = bo[gcol];
#pragma unroll
            for (int r = 0; r < 4; r++) {
                int grow = blockIdx.x * 128 + wm * 64 + mi * 16 + quad * 4 + r;
                out[(size_t)grow * D_MODEL + gcol] = acc[mi][ni][r] + bcol;
            }
        }
    }
}

// ---------- flash attention v11: fused dual-chain (shared K/V LDS reads) ----------
// v10's XCD-affine mapping + R4 layout + depth-2 K prefetch kept intact.
// v11 change: the two paired q-tiles (qtA=31-x >= qtB=x) now run as TWO CHAINS in
// ONE kt loop. Chain B's kt range [0, x] is a subset of chain A's [0, 31-x], so:
//   - each K/V tile is staged ONCE (33 -> 32-x staged tiles per block, -26% DMA)
//   - each kf/vbf ds_read_b128 feeds BOTH chains' MFMAs (LDS reads per MFMA ~halved
//     on dual-active tiles). Theory: attn is LDS-pipe bound (~77% b128 port util).
// Per-CU balance: blocks n and n+256 co-reside (same XCD); x-permutation pairs
// (x, 15-x) there -> per-CU LDS load is constant AND both blocks share one bh.
// DMA/vmcnt pattern per iteration is unchanged from v8/v10 (2 V + 2 K, vmcnt(2)).
#define PIPE_WAIT2_BARRIER() do { asm volatile("s_waitcnt vmcnt(2)" ::: "memory"); __builtin_amdgcn_s_barrier(); } while (0)
#define PIPE_WAIT0_BARRIER() do { asm volatile("s_waitcnt vmcnt(0)" ::: "memory"); __builtin_amdgcn_s_barrier(); } while (0)

__device__ __forceinline__ void flash_pair(
    int qtA, int qtB, int bh, int b, int h, int L,
    const uint16_t* __restrict__ Qh, const uint16_t* __restrict__ Kh, const uint16_t* __restrict__ Vth,
    uint16_t* __restrict__ attn,
    uint16_t* KtA, uint16_t* VtA, uint16_t* PtwA, uint16_t* PtwB) {
    const f32x4 fzero = {0.f, 0.f, 0.f, 0.f};
    const float MFIX = 6.0f;
    int tid = threadIdx.x, lane = tid & 63, w = tid >> 6;
    int l15 = lane & 15, quad = lane >> 4, l7 = l15 & 7;
    int q0A = qtA * 64, q0B = qtB * 64;
    int rl = lane >> 3, cb8 = lane & 7;

    f16x8 ones;
#pragma unroll
    for (int j = 0; j < 8; j++) ones[j] = (_Float16)1.0f;

    f16x8 qfA[2], qfB[2];
#pragma unroll
    for (int ks = 0; ks < 2; ks++) {
        qfA[ks] = *(const f16x8*)(Qh + ((size_t)bh * SEQ + q0A + w * 16 + l15) * 64 + ks * 32 + quad * 8);
        qfB[ks] = *(const f16x8*)(Qh + ((size_t)bh * SEQ + q0B + w * 16 + l15) * 64 + ks * 32 + quad * 8);
    }

    f32x4 oA[4], oB[4], lAcc = fzero, lBcc = fzero;
#pragma unroll
    for (int ni = 0; ni < 4; ni++) { oA[ni] = fzero; oB[ni] = fzero; }

    int nkt_p = (L + 63) >> 6;
    int nktA = (qtA + 1 < nkt_p) ? (qtA + 1) : nkt_p;
    int nktB = (qtB + 1 < nkt_p) ? (qtB + 1) : nkt_p;  // <= nktA (qtB<=15<=qtA, nkt_p>=24)

    const uint16_t* Kbh = Kh + (size_t)bh * SEQ * 64;
    const uint16_t* Vbh = Vth + ((size_t)bh << 6) * SEQ;

    auto stageK = [&](int kt_, int slot) {
#pragma unroll
        for (int i_ = 0; i_ < 2; ++i_) {
            int d8 = w * 2 + i_;
            int row = d8 * 8 + rl;
            int cbg = cb8 ^ rl;
            lds_dma16(Kbh + (size_t)(kt_ * 64 + row) * 64 + cbg * 8, KtA + slot * 4096 + d8 * 512);
        }
    };
    auto stageV = [&](int kt_, int slot) {
#pragma unroll
        for (int i_ = 0; i_ < 2; ++i_) {
            int d8 = w * 2 + i_;
            int row = d8 * 8 + rl;
            int cbg = cb8 ^ rl;
            lds_dma16(Vbh + (size_t)row * SEQ + kt_ * 64 + cbg * 8, VtA + slot * 4096 + d8 * 512);
        }
    };

    // prologue: V0,K0 drained; K1 left in flight (steady-state invariant)
    stageV(0, 0);
    stageK(0, 0);
    PIPE_WAIT0_BARRIER();
    stageK((1 < nktA) ? 1 : 0, 1);

    int kcur = 0, vcur = 0;
    for (int kt = 0; kt < nktA; ++kt) {
        int ktV = (kt + 1 < nktA) ? kt + 1 : nktA - 1;
        int ktK = (kt + 2 < nktA) ? kt + 2 : nktA - 1;
        stageV(ktV, (kt + 1) & 1);            // issued FIRST: retired by vmcnt(2) below
        int ks2 = (kcur >= 1) ? kcur - 1 : 2; // (kcur+2)%3
        stageK(ktK, ks2);

        const uint16_t* Kc = KtA + kcur * 4096;
        const uint16_t* Vc = VtA + vcur * 4096;
        bool actB = (kt < nktB);

        // ---- S = Q K^T for both chains; kf read ONCE per ks ----
        f32x4 sA[4], sB[4];
#pragma unroll
        for (int ni = 0; ni < 4; ni++) { sA[ni] = fzero; sB[ni] = fzero; }
        __builtin_amdgcn_s_setprio(1);
#pragma unroll
        for (int ks = 0; ks < 2; ks++) {
            f16x8 kf[4];
#pragma unroll
            for (int ni = 0; ni < 4; ni++) {
                int row = ni * 16 + l15;
                kf[ni] = *(const f16x8*)(Kc + row * 64 + (((ks * 4 + quad) ^ (row & 7)) * 8));
            }
#pragma unroll
            for (int ni = 0; ni < 4; ni++)
                sA[ni] = __builtin_amdgcn_mfma_f32_16x16x32_f16(qfA[ks], kf[ni], sA[ni], 0, 0, 0);
            if (actB) {
#pragma unroll
                for (int ni = 0; ni < 4; ni++)
                    sB[ni] = __builtin_amdgcn_mfma_f32_16x16x32_f16(qfB[ks], kf[ni], sB[ni], 0, 0, 0);
            }
        }
        __builtin_amdgcn_s_setprio(0);

        // ---- fixed-max softmax: p = exp2(s - MFIX), straight to LDS ----
        {
            bool fullA = (kt < qtA) && (kt * 64 + 64 <= L);
#pragma unroll
            for (int r = 0; r < 4; r++) {
                int prow = quad * 4 + r;
                int q_idx = q0A + w * 16 + prow;
                int pr7 = prow & 7;
#pragma unroll
                for (int ni = 0; ni < 4; ni++) {
                    float s = sA[ni][r];
                    if (!fullA) {
                        int key = kt * 64 + ni * 16 + l15;
                        s = ((key <= q_idx) && (key < L)) ? s : -1e9f;
                    }
                    float p = fexp2(s - MFIX);
                    int cb = ni * 2 + (l15 >> 3);
                    PtwA[prow * 64 + ((cb ^ pr7) * 8) + l7] = f2h(p);
                }
            }
        }
        if (actB) {
            bool fullB = (kt < qtB) && (kt * 64 + 64 <= L);
#pragma unroll
            for (int r = 0; r < 4; r++) {
                int prow = quad * 4 + r;
                int q_idx = q0B + w * 16 + prow;
                int pr7 = prow & 7;
#pragma unroll
                for (int ni = 0; ni < 4; ni++) {
                    float s = sB[ni][r];
                    if (!fullB) {
                        int key = kt * 64 + ni * 16 + l15;
                        s = ((key <= q_idx) && (key < L)) ? s : -1e9f;
                    }
                    float p = fexp2(s - MFIX);
                    int cb = ni * 2 + (l15 >> 3);
                    PtwB[prow * 64 + ((cb ^ pr7) * 8) + l7] = f2h(p);
                }
            }
        }
        __asm__ __volatile__("" ::: "memory");  // order wave-private Pt stores vs loads

        // ---- O += P V ; l += P . 1 ; vbf read ONCE per ks ----
        __builtin_amdgcn_s_setprio(1);
#pragma unroll
        for (int ks = 0; ks < 2; ks++) {
            f16x8 paA = *(const f16x8*)(PtwA + l15 * 64 + (((ks * 4 + quad) ^ l7) * 8));
            lAcc = __builtin_amdgcn_mfma_f32_16x16x32_f16(paA, ones, lAcc, 0, 0, 0);
            f16x8 paB;
            if (actB) {
                paB = *(const f16x8*)(PtwB + l15 * 64 + (((ks * 4 + quad) ^ l7) * 8));
                lBcc = __builtin_amdgcn_mfma_f32_16x16x32_f16(paB, ones, lBcc, 0, 0, 0);
            }
            f16x8 vbf[4];
#pragma unroll
            for (int ni = 0; ni < 4; ni++) {
                int row = ni * 16 + l15;
                vbf[ni] = *(const f16x8*)(Vc + row * 64 + (((ks * 4 + quad) ^ (row & 7)) * 8));
            }
#pragma unroll
            for (int ni = 0; ni < 4; ni++)
                oA[ni] = __builtin_amdgcn_mfma_f32_16x16x32_f16(paA, vbf[ni], oA[ni], 0, 0, 0);
            if (actB) {
#pragma unroll
                for (int ni = 0; ni < 4; ni++)
                    oB[ni] = __builtin_amdgcn_mfma_f32_16x16x32_f16(paB, vbf[ni], oB[ni], 0, 0, 0);
            }
        }
        __builtin_amdgcn_s_setprio(0);

        PIPE_WAIT2_BARRIER();
        kcur = (kcur == 2) ? 0 : kcur + 1;
        vcur ^= 1;
    }

    // ---- epilogues: O / l ----
#pragma unroll
    for (int r = 0; r < 4; r++) {
        float inv = 1.0f / lAcc[r];
        int q_idx = q0A + w * 16 + quad * 4 + r;
#pragma unroll
        for (int ni = 0; ni < 4; ni++) {
            attn[((size_t)(b * SEQ + q_idx)) * D_MODEL + h * 64 + ni * 16 + l15] =
                f2h(oA[ni][r] * inv);
        }
    }
#pragma unroll
    for (int r = 0; r < 4; r++) {
        float inv = 1.0f / lBcc[r];
        int q_idx = q0B + w * 16 + quad * 4 + r;
#pragma unroll
        for (int ni = 0; ni < 4; ni++) {
            attn[((size_t)(b * SEQ + q_idx)) * D_MODEL + h * 64 + ni * 16 + l15] =
                f2h(oB[ni][r] * inv);
        }
    }
}

__global__ __launch_bounds__(256, 2) void attn_kernel(
    const uint16_t* __restrict__ Qh, const uint16_t* __restrict__ Kh, const uint16_t* __restrict__ Vth,
    uint16_t* __restrict__ attn, const int* __restrict__ lens) {
    __shared__ uint16_t Kt[3 * 4096];  // 24KB: K tiles, prefetch distance 2
    __shared__ uint16_t Vt[2 * 4096];  // 16KB: V tiles, prefetch distance 1
    __shared__ uint16_t Pt[8 * 1024];  // 16KB: wave-private P strips, 2 chains
    // XCD-affine decode (v10): XCD = n%8; all 16 blocks of a head on one XCD.
    // v11 x-permutation: co-resident blocks n and n+256 (i, i+32 -> j, j+8) get
    // x and 15-x -> per-CU LDS load constant; same head slot -> same bh on the CU.
    int n = (int)blockIdx.x;
    int xcd = n & 7;
    int i = n >> 3;                     // 0..63
    int hs = i & 3;                     // head slot
    int j = i >> 2;                     // 0..15
    int x = (j < 8) ? j : (23 - j);     // j,j+8 -> x,15-x (bijective over 0..15)
    int jj = (xcd << 2) | hs;           // 0..31
    int bh = ((jj & 1) << 4) | (jj >> 1); // 2 heads from each batch per XCD
    int b = bh >> 4, h = bh & 15;
    int L = lens[b];
    int w = threadIdx.x >> 6;
    uint16_t* PtwA = Pt + w * 2048;
    uint16_t* PtwB = PtwA + 1024;
    // fused dual-chain: qtA = 31-x (16..31), qtB = x (0..15); B's kt range  A's
    flash_pair(31 - x, x, bh, b, h, L, Qh, Kh, Vth, attn, Kt, Vt, PtwA, PtwB);
}

extern "C" void kernel_launch(void* const* d_in, const int* in_sizes, int n_in,
                              void* d_out, int out_size, void* d_ws, size_t ws_size,
                              hipStream_t stream) {
    const float* q  = (const float*)d_in[0];
    const float* k  = (const float*)d_in[1];
    const float* v  = (const float*)d_in[2];
    const int*   mask = (const int*)d_in[3];
    const float* Wq = (const float*)d_in[4];
    const float* bq = (const float*)d_in[5];
    const float* Wk = (const float*)d_in[6];
    const float* bk = (const float*)d_in[7];
    const float* Wv = (const float*)d_in[8];
    const float* bv = (const float*)d_in[9];
    const float* Wo = (const float*)d_in[10];
    const float* bo = (const float*)d_in[11];
    float* out = (float*)d_out;

    char* ws = (char*)d_ws;
    size_t off = 0;
    auto alloc = [&](size_t bytes) -> char* {
        char* p = ws + off;
        off += (bytes + 255) & ~(size_t)255;
        return p;
    };
    const size_t inp_e = (size_t)NROW * D_MODEL;
    const size_t w_e   = (size_t)D_MODEL * D_MODEL;
    uint16_t* qbf  = (uint16_t*)alloc(inp_e * 2);
    uint16_t* kbf  = (uint16_t*)alloc(inp_e * 2);
    uint16_t* vbf  = (uint16_t*)alloc(inp_e * 2);
    uint16_t* wqb  = (uint16_t*)alloc(w_e * 2);
    uint16_t* wkb  = (uint16_t*)alloc(w_e * 2);
    uint16_t* wvb  = (uint16_t*)alloc(w_e * 2);
    uint16_t* wob  = (uint16_t*)alloc(w_e * 2);
    uint16_t* Qhb  = (uint16_t*)alloc(inp_e * 2);
    uint16_t* Khb  = (uint16_t*)alloc(inp_e * 2);
    uint16_t* Vtb  = (uint16_t*)alloc(inp_e * 2);
    uint16_t* attb = (uint16_t*)alloc(inp_e * 2);
    int* lens      = (int*)alloc(256);

    CvtArgs ca;
    ca.src[0] = q;  ca.dst[0] = qbf; ca.n4[0] = (int)(inp_e / 4);
    ca.src[1] = k;  ca.dst[1] = kbf; ca.n4[1] = (int)(inp_e / 4);
    ca.src[2] = v;  ca.dst[2] = vbf; ca.n4[2] = (int)(inp_e / 4);
    ca.src[3] = Wq; ca.dst[3] = wqb; ca.n4[3] = (int)(w_e / 4);
    ca.src[4] = Wk; ca.dst[4] = wkb; ca.n4[4] = (int)(w_e / 4);
    ca.src[5] = Wv; ca.dst[5] = wvb; ca.n4[5] = (int)(w_e / 4);
    ca.src[6] = Wo; ca.dst[6] = wob; ca.n4[6] = (int)(w_e / 4);
    cvt_all_kernel<<<dim3(128, 8), 256, 0, stream>>>(ca, mask, lens);

    qkv_kernel<<<dim3(32, 8, 3), 256, 0, stream>>>(qbf, kbf, vbf, wqb, wkb, wvb,
                                                   bq, bk, bv, Qhb, Khb, Vtb);
    attn_kernel<<<dim3(512, 1), 256, 0, stream>>>(Qhb, Khb, Vtb, attb, lens);
    outproj_kernel<<<dim3(32, 8), 256, 0, stream>>>(attb, wob, bo, out);
}

// Round 4
// 224.904 us; speedup vs baseline: 1.0458x; 1.0458x over previous
//
#include <hip/hip_runtime.h>
#include <stdint.h>

#define D_MODEL 1024
#define NHEAD 16
#define DK 64
#define BATCH 2
#define SEQ 2048
#define NROW 4096  // BATCH*SEQ

typedef __attribute__((ext_vector_type(8))) _Float16 f16x8;
typedef __attribute__((ext_vector_type(4))) float f32x4;

__device__ __forceinline__ uint16_t f2h(float x) {
    _Float16 h = (_Float16)x;
    union { _Float16 h; uint16_t u; } cv;
    cv.h = h;
    return cv.u;
}

__device__ __forceinline__ float fexp2(float x) {
#if __has_builtin(__builtin_amdgcn_exp2f)
    return __builtin_amdgcn_exp2f(x);
#else
    return exp2f(x);
#endif
}

// async global->LDS DMA, 16B per lane, LDS dst = wave-uniform base + lane*16
__device__ __forceinline__ void lds_dma16(const uint16_t* g, uint16_t* l) {
    __builtin_amdgcn_global_load_lds((const __attribute__((address_space(1))) void*)g,
                                     (__attribute__((address_space(3))) void*)l,
                                     16, 0, 0);
}

// ---------- merged f32->f16 conversion (y=0..6) + mask->lens (y=7) ----------
struct CvtArgs {
    const float* src[7];
    uint16_t* dst[7];
    int n4[7];
};
__global__ void cvt_all_kernel(CvtArgs a, const int* __restrict__ mask, int* __restrict__ lens) {
    int t = blockIdx.y;
    if (t == 7) {
        if (blockIdx.x != 0) return;
        __shared__ int red[256];
        int tid = threadIdx.x;
        int mx = 0;
        for (int i = tid; i < 1024; i += 256) { int v = mask[i]; if (v > mx) mx = v; }
        red[tid] = mx; __syncthreads();
        for (int s = 128; s > 0; s >>= 1) { if (tid < s) { if (red[tid+s] > red[tid]) red[tid] = red[tid+s]; } __syncthreads(); }
        int bytemode = (red[0] > 1);
        __syncthreads();
        const unsigned char* mb = (const unsigned char*)mask;
        for (int b = 0; b < BATCH; ++b) {
            int cnt = 0;
            for (int tt = tid; tt < SEQ; tt += 256) {
                int v = bytemode ? (int)mb[b*SEQ + tt] : mask[b*SEQ + tt];
                cnt += (v != 0) ? 1 : 0;
            }
            red[tid] = cnt; __syncthreads();
            for (int s = 128; s > 0; s >>= 1) { if (tid < s) red[tid] += red[tid+s]; __syncthreads(); }
            if (tid == 0) lens[b] = red[0];
            __syncthreads();
        }
        return;
    }
    const float* src = a.src[t];
    uint16_t* dst = a.dst[t];
    int n4 = a.n4[t];
    int i = blockIdx.x * blockDim.x + threadIdx.x;
    int stride = gridDim.x * blockDim.x;
    for (; i < n4; i += stride) {
        float4 v = ((const float4*)src)[i];
        ushort4 o;
        o.x = f2h(v.x); o.y = f2h(v.y); o.z = f2h(v.z); o.w = f2h(v.w);
        ((ushort4*)dst)[i] = o;
    }
}

// ---------- 128x128 NT GEMM core, BK=64, global_load_lds + XOR-swizzled LDS ----------
__device__ __forceinline__ void gemm_tile_core(const uint16_t* __restrict__ A,
                                               const uint16_t* __restrict__ W,
                                               int bx, int by,
                                               uint16_t* As, uint16_t* Bs,
                                               f32x4 (&acc)[4][4]) {
    const f32x4 fzero = {0.f, 0.f, 0.f, 0.f};
    int tid = threadIdx.x;
    int lane = tid & 63, wave = tid >> 6;
    int wm = wave >> 1, wn = wave & 1;
    int l15 = lane & 15, quad = lane >> 4;
    int rl = lane >> 3, cb8 = lane & 7;  // DMA: 1KB chunk = 8 rows x 128B
#pragma unroll
    for (int mi = 0; mi < 4; mi++)
#pragma unroll
        for (int ni = 0; ni < 4; ni++) acc[mi][ni] = fzero;

    for (int k0 = 0; k0 < D_MODEL; k0 += 64) {
        __syncthreads();
#pragma unroll
        for (int i = 0; i < 4; ++i) {
            int d8 = wave * 4 + i;
            int row = d8 * 8 + rl;
            int cbg = cb8 ^ rl;
            lds_dma16(A + (size_t)(bx * 128 + row) * D_MODEL + k0 + cbg * 8, As + d8 * 512);
            lds_dma16(W + (size_t)(by * 128 + row) * D_MODEL + k0 + cbg * 8, Bs + d8 * 512);
        }
        __syncthreads();
#pragma unroll
        for (int ks = 0; ks < 2; ks++) {
            f16x8 af[4], bf[4];
#pragma unroll
            for (int mi = 0; mi < 4; mi++) {
                int row = wm * 64 + mi * 16 + l15;
                af[mi] = *(const f16x8*)(As + row * 64 + (((ks * 4 + quad) ^ (row & 7)) * 8));
            }
#pragma unroll
            for (int ni = 0; ni < 4; ni++) {
                int row = wn * 64 + ni * 16 + l15;
                bf[ni] = *(const f16x8*)(Bs + row * 64 + (((ks * 4 + quad) ^ (row & 7)) * 8));
            }
#pragma unroll
            for (int mi = 0; mi < 4; mi++)
#pragma unroll
                for (int ni = 0; ni < 4; ni++)
                    acc[mi][ni] = __builtin_amdgcn_mfma_f32_16x16x32_f16(af[mi], bf[ni], acc[mi][ni], 0, 0, 0);
        }
    }
}

// ---------- QKV projection; V goes through LDS transpose (aliased) ----------
#define TS_STRIDE 136  // u16; 272B rows -> 16B aligned, odd-word bank spread
__global__ __launch_bounds__(256, 3) void qkv_kernel(
    const uint16_t* __restrict__ qb, const uint16_t* __restrict__ kb, const uint16_t* __restrict__ vb,
    const uint16_t* __restrict__ wq, const uint16_t* __restrict__ wk, const uint16_t* __restrict__ wv,
    const float* __restrict__ bq, const float* __restrict__ bk, const float* __restrict__ bv,
    uint16_t* __restrict__ Qh, uint16_t* __restrict__ Kh, uint16_t* __restrict__ Vth) {
    __shared__ uint16_t smem[TS_STRIDE * 128];  // 34816B >= As+Bs (32KB) or Ts
    uint16_t* As = smem;
    uint16_t* Bs = smem + 128 * 64;
    int v = blockIdx.z;
    const uint16_t* A = (v == 0) ? qb : ((v == 1) ? kb : vb);
    const uint16_t* W = (v == 0) ? wq : ((v == 1) ? wk : wv);
    const float* bias = (v == 0) ? bq : ((v == 1) ? bk : bv);
    f32x4 acc[4][4];
    gemm_tile_core(A, W, blockIdx.x, blockIdx.y, As, Bs, acc);

    int tid = threadIdx.x, lane = tid & 63, wave = tid >> 6;
    int wm = wave >> 1, wn = wave & 1, l15 = lane & 15, quad = lane >> 4;
    // Q pre-scale folds 1/sqrt(dk) AND log2(e) so attention uses raw exp2.
    const float QSCALE = 0.125f * 1.44269504088896f;

    if (v == 2) {
        __syncthreads();  // all waves done reading As/Bs before aliasing as Ts
        uint16_t* Ts = smem;
#pragma unroll
        for (int mi = 0; mi < 4; mi++) {
#pragma unroll
            for (int ni = 0; ni < 4; ni++) {
                int col = wn * 64 + ni * 16 + l15;
                float bcol = bias[blockIdx.y * 128 + col];
#pragma unroll
                for (int r = 0; r < 4; r++) {
                    int tl = wm * 64 + mi * 16 + quad * 4 + r;
                    Ts[col * TS_STRIDE + tl] = f2h(acc[mi][ni][r] + bcol);
                }
            }
        }
        __syncthreads();
        int col = tid >> 1, th = (tid & 1) << 6;
        int gcol = blockIdx.y * 128 + col;
        int h = gcol >> 6, d = gcol & 63;
        int grow0 = blockIdx.x * 128;
        int b = grow0 >> 11, t = (grow0 & (SEQ - 1)) + th;
        size_t base = (((size_t)(b * NHEAD + h) << 6) + d) * SEQ + t;
#pragma unroll
        for (int j = 0; j < 8; j++)
            *(uint4*)(Vth + base + j * 8) = *(const uint4*)(Ts + col * TS_STRIDE + th + j * 8);
        return;
    }

#pragma unroll
    for (int mi = 0; mi < 4; mi++) {
#pragma unroll
        for (int ni = 0; ni < 4; ni++) {
            int gcol = blockIdx.y * 128 + wn * 64 + ni * 16 + l15;
            float bcol = bias[gcol];
            int h = gcol >> 6, d = gcol & 63;
#pragma unroll
            for (int r = 0; r < 4; r++) {
                int grow = blockIdx.x * 128 + wm * 64 + mi * 16 + quad * 4 + r;
                int b = grow >> 11, t = grow & (SEQ - 1);
                float val = acc[mi][ni][r] + bcol;
                size_t bh = (size_t)(b * NHEAD + h);
                if (v == 0) Qh[(bh * SEQ + t) * 64 + d] = f2h(val * QSCALE);
                else        Kh[(bh * SEQ + t) * 64 + d] = f2h(val);
            }
        }
    }
}

// ---------- output projection ----------
__global__ __launch_bounds__(256, 3) void outproj_kernel(
    const uint16_t* __restrict__ attn, const uint16_t* __restrict__ wo,
    const float* __restrict__ bo, float* __restrict__ out) {
    __shared__ uint16_t As[128 * 64], Bs[128 * 64];
    f32x4 acc[4][4];
    gemm_tile_core(attn, wo, blockIdx.x, blockIdx.y, As, Bs, acc);
    int tid = threadIdx.x, lane = tid & 63, wave = tid >> 6;
    int wm = wave >> 1, wn = wave & 1, l15 = lane & 15, quad = lane >> 4;
#pragma unroll
    for (int mi = 0; mi < 4; mi++) {
#pragma unroll
        for (int ni = 0; ni < 4; ni++) {
            int gcol = blockIdx.y * 128 + wn * 64 + ni * 16 + l15;
            float bcol = bo[gcol];
#pragma unroll
            for (int r = 0; r < 4; r++) {
                int grow = blockIdx.x * 128 + wm * 64 + mi * 16 + quad * 4 + r;
                out[(size_t)grow * D_MODEL + gcol] = acc[mi][ni][r] + bcol;
            }
        }
    }
}

// ---------- flash attention v12: v10 structure + setprio-only (single change) ----------
// v10 = v8 R4 layout + depth-2 K prefetch + partial-drain barriers + XCD-affine bh map.
// Per tile, issue order (per wave): V(kt+1) [2 DMAs] then K(kt+2) [2 DMAs].
// Steady-state outstanding at tile end: K(kt+1)[2] V(kt+1)[2] K(kt+2)[2] = 6;
// `s_waitcnt vmcnt(2)` retires the 4 oldest (exactly what tile kt+1 needs) and
// leaves K(kt+2) in flight across the barrier -> no full vmcnt(0) drain in the loop.
// Tail tiles stage clamped dummies so the count pattern stays uniform.
// v12 change (ONLY): s_setprio(1) around the QK and PV MFMA clusters. The two
// co-resident blocks per CU are phase-independent (m191 regime: +4-7%); if this
// regresses, setprio was v11's poison and the v10 loop is schedule-optimal.
// v11 post-mortem: dual-chain + setprio + co-residency-dependent balance bundled;
// regressed 46->54us. LDS-read reduction did NOT help => not LDS-throughput-bound.
#define PIPE_WAIT2_BARRIER() do { asm volatile("s_waitcnt vmcnt(2)" ::: "memory"); __builtin_amdgcn_s_barrier(); } while (0)
#define PIPE_WAIT0_BARRIER() do { asm volatile("s_waitcnt vmcnt(0)" ::: "memory"); __builtin_amdgcn_s_barrier(); } while (0)

__device__ __forceinline__ void flash_item(
    int qt, int bh, int b, int h, int L,
    const uint16_t* __restrict__ Qh, const uint16_t* __restrict__ Kh, const uint16_t* __restrict__ Vth,
    uint16_t* __restrict__ attn,
    uint16_t* KtA, uint16_t* VtA, uint16_t* Ptw) {
    const f32x4 fzero = {0.f, 0.f, 0.f, 0.f};
    const float MFIX = 6.0f;
    int tid = threadIdx.x, lane = tid & 63, w = tid >> 6;
    int l15 = lane & 15, quad = lane >> 4, l7 = l15 & 7;
    int q0 = qt * 64;
    int rl = lane >> 3, cb8 = lane & 7;

    f16x8 ones;
#pragma unroll
    for (int j = 0; j < 8; j++) ones[j] = (_Float16)1.0f;

    f16x8 qf[2];
#pragma unroll
    for (int ks = 0; ks < 2; ks++)
        qf[ks] = *(const f16x8*)(Qh + ((size_t)bh * SEQ + q0 + w * 16 + l15) * 64 + ks * 32 + quad * 8);

    f32x4 o_acc[4], l_acc = fzero;
#pragma unroll
    for (int ni = 0; ni < 4; ni++) o_acc[ni] = fzero;

    int nkt_p = (L + 63) >> 6;
    int nkt = (qt + 1 < nkt_p) ? (qt + 1) : nkt_p;

    const uint16_t* Kbh = Kh + (size_t)bh * SEQ * 64;
    const uint16_t* Vbh = Vth + ((size_t)bh << 6) * SEQ;

    auto stageK = [&](int kt_, int slot) {
#pragma unroll
        for (int i_ = 0; i_ < 2; ++i_) {
            int d8 = w * 2 + i_;
            int row = d8 * 8 + rl;
            int cbg = cb8 ^ rl;
            lds_dma16(Kbh + (size_t)(kt_ * 64 + row) * 64 + cbg * 8, KtA + slot * 4096 + d8 * 512);
        }
    };
    auto stageV = [&](int kt_, int slot) {
#pragma unroll
        for (int i_ = 0; i_ < 2; ++i_) {
            int d8 = w * 2 + i_;
            int row = d8 * 8 + rl;
            int cbg = cb8 ^ rl;
            lds_dma16(Vbh + (size_t)row * SEQ + kt_ * 64 + cbg * 8, VtA + slot * 4096 + d8 * 512);
        }
    };

    // prologue: V0,K0 drained; K1 left in flight (steady-state invariant)
    stageV(0, 0);
    stageK(0, 0);
    PIPE_WAIT0_BARRIER();
    stageK((1 < nkt) ? 1 : 0, 1);

    int kcur = 0, vcur = 0;
    for (int kt = 0; kt < nkt; ++kt) {
        int ktV = (kt + 1 < nkt) ? kt + 1 : nkt - 1;
        int ktK = (kt + 2 < nkt) ? kt + 2 : nkt - 1;
        stageV(ktV, (kt + 1) & 1);            // issued FIRST: retired by vmcnt(2) below
        int ks2 = (kcur >= 1) ? kcur - 1 : 2; // (kcur+2)%3
        stageK(ktK, ks2);

        const uint16_t* Kc = KtA + kcur * 4096;
        const uint16_t* Vc = VtA + vcur * 4096;

        // ---- S = Q K^T (log2-domain; scale folded into Q) ----
        f32x4 s_acc[4];
#pragma unroll
        for (int ni = 0; ni < 4; ni++) s_acc[ni] = fzero;
        __builtin_amdgcn_s_setprio(1);
#pragma unroll
        for (int ks = 0; ks < 2; ks++) {
            f16x8 kf[4];
#pragma unroll
            for (int ni = 0; ni < 4; ni++) {
                int row = ni * 16 + l15;
                kf[ni] = *(const f16x8*)(Kc + row * 64 + (((ks * 4 + quad) ^ (row & 7)) * 8));
            }
#pragma unroll
            for (int ni = 0; ni < 4; ni++)
                s_acc[ni] = __builtin_amdgcn_mfma_f32_16x16x32_f16(qf[ks], kf[ni], s_acc[ni], 0, 0, 0);
        }
        __builtin_amdgcn_s_setprio(0);

        // ---- fixed-max softmax: p = exp2(s - MFIX), straight to LDS ----
        bool full = (kt < qt) && (kt * 64 + 64 <= L);
#pragma unroll
        for (int r = 0; r < 4; r++) {
            int prow = quad * 4 + r;
            int q_idx = q0 + w * 16 + prow;
            int pr7 = prow & 7;
#pragma unroll
            for (int ni = 0; ni < 4; ni++) {
                float s = s_acc[ni][r];
                if (!full) {
                    int key = kt * 64 + ni * 16 + l15;
                    s = ((key <= q_idx) && (key < L)) ? s : -1e9f;
                }
                float p = fexp2(s - MFIX);
                int cb = ni * 2 + (l15 >> 3);
                Ptw[prow * 64 + ((cb ^ pr7) * 8) + l7] = f2h(p);
            }
        }
        __asm__ __volatile__("" ::: "memory");  // order wave-private Pt stores vs loads

        // ---- O += P V ; l += P . 1 ----
        __builtin_amdgcn_s_setprio(1);
#pragma unroll
        for (int ks = 0; ks < 2; ks++) {
            f16x8 pa = *(const f16x8*)(Ptw + l15 * 64 + (((ks * 4 + quad) ^ l7) * 8));
            l_acc = __builtin_amdgcn_mfma_f32_16x16x32_f16(pa, ones, l_acc, 0, 0, 0);
            f16x8 vbf[4];
#pragma unroll
            for (int ni = 0; ni < 4; ni++) {
                int row = ni * 16 + l15;
                vbf[ni] = *(const f16x8*)(Vc + row * 64 + (((ks * 4 + quad) ^ (row & 7)) * 8));
            }
#pragma unroll
            for (int ni = 0; ni < 4; ni++)
                o_acc[ni] = __builtin_amdgcn_mfma_f32_16x16x32_f16(pa, vbf[ni], o_acc[ni], 0, 0, 0);
        }
        __builtin_amdgcn_s_setprio(0);

        PIPE_WAIT2_BARRIER();
        kcur = (kcur == 2) ? 0 : kcur + 1;
        vcur ^= 1;
    }

    // ---- epilogue: O / l ----
#pragma unroll
    for (int r = 0; r < 4; r++) {
        float inv = 1.0f / l_acc[r];
        int q_idx = q0 + w * 16 + quad * 4 + r;
#pragma unroll
        for (int ni = 0; ni < 4; ni++) {
            attn[((size_t)(b * SEQ + q_idx)) * D_MODEL + h * 64 + ni * 16 + l15] =
                f2h(o_acc[ni][r] * inv);
        }
    }
}

__global__ __launch_bounds__(256, 3) void attn_kernel(
    const uint16_t* __restrict__ Qh, const uint16_t* __restrict__ Kh, const uint16_t* __restrict__ Vth,
    uint16_t* __restrict__ attn, const int* __restrict__ lens) {
    __shared__ uint16_t Kt[3 * 4096];  // 24KB: K tiles, prefetch distance 2
    __shared__ uint16_t Vt[2 * 4096];  // 16KB: V tiles, prefetch distance 1
    __shared__ uint16_t Pt[4 * 1024];  // 8KB: wave-private P strips
    // v10 XCD-affine decode: XCD = n%8 (HW round-robin). Each XCD gets 4 heads,
    // all 16 q-tile blocks of a head on one XCD -> K/V L2-resident (2MB/XCD).
    // j = head slot 0..31; bh = (j&1)*16 + (j>>1) interleaves batches per XCD.
    int n = (int)blockIdx.x;
    int xcd = n & 7;
    int i = n >> 3;                     // 0..63
    int j = (xcd << 2) | (i & 3);       // 0..31
    int bh = ((j & 1) << 4) | (j >> 1); // bijective: 2 heads each batch per XCD
    int x = i >> 2;                     // 0..15
    int b = bh >> 4, h = bh & 15;
    int L = lens[b];
    int w = threadIdx.x >> 6;
    uint16_t* Ptw = Pt + w * 1024;
    // deterministic balance: pair (31-x, x) => 33 kt-tiles per block
    flash_item(31 - x, bh, b, h, L, Qh, Kh, Vth, attn, Kt, Vt, Ptw);
    flash_item(x, bh, b, h, L, Qh, Kh, Vth, attn, Kt, Vt, Ptw);
}

extern "C" void kernel_launch(void* const* d_in, const int* in_sizes, int n_in,
                              void* d_out, int out_size, void* d_ws, size_t ws_size,
                              hipStream_t stream) {
    const float* q  = (const float*)d_in[0];
    const float* k  = (const float*)d_in[1];
    const float* v  = (const float*)d_in[2];
    const int*   mask = (const int*)d_in[3];
    const float* Wq = (const float*)d_in[4];
    const float* bq = (const float*)d_in[5];
    const float* Wk = (const float*)d_in[6];
    const float* bk = (const float*)d_in[7];
    const float* Wv = (const float*)d_in[8];
    const float* bv = (const float*)d_in[9];
    const float* Wo = (const float*)d_in[10];
    const float* bo = (const float*)d_in[11];
    float* out = (float*)d_out;

    char* ws = (char*)d_ws;
    size_t off = 0;
    auto alloc = [&](size_t bytes) -> char* {
        char* p = ws + off;
        off += (bytes + 255) & ~(size_t)255;
        return p;
    };
    const size_t inp_e = (size_t)NROW * D_MODEL;
    const size_t w_e   = (size_t)D_MODEL * D_MODEL;
    uint16_t* qbf  = (uint16_t*)alloc(inp_e * 2);
    uint16_t* kbf  = (uint16_t*)alloc(inp_e * 2);
    uint16_t* vbf  = (uint16_t*)alloc(inp_e * 2);
    uint16_t* wqb  = (uint16_t*)alloc(w_e * 2);
    uint16_t* wkb  = (uint16_t*)alloc(w_e * 2);
    uint16_t* wvb  = (uint16_t*)alloc(w_e * 2);
    uint16_t* wob  = (uint16_t*)alloc(w_e * 2);
    uint16_t* Qhb  = (uint16_t*)alloc(inp_e * 2);
    uint16_t* Khb  = (uint16_t*)alloc(inp_e * 2);
    uint16_t* Vtb  = (uint16_t*)alloc(inp_e * 2);
    uint16_t* attb = (uint16_t*)alloc(inp_e * 2);
    int* lens      = (int*)alloc(256);

    CvtArgs ca;
    ca.src[0] = q;  ca.dst[0] = qbf; ca.n4[0] = (int)(inp_e / 4);
    ca.src[1] = k;  ca.dst[1] = kbf; ca.n4[1] = (int)(inp_e / 4);
    ca.src[2] = v;  ca.dst[2] = vbf; ca.n4[2] = (int)(inp_e / 4);
    ca.src[3] = Wq; ca.dst[3] = wqb; ca.n4[3] = (int)(w_e / 4);
    ca.src[4] = Wk; ca.dst[4] = wkb; ca.n4[4] = (int)(w_e / 4);
    ca.src[5] = Wv; ca.dst[5] = wvb; ca.n4[5] = (int)(w_e / 4);
    ca.src[6] = Wo; ca.dst[6] = wob; ca.n4[6] = (int)(w_e / 4);
    cvt_all_kernel<<<dim3(128, 8), 256, 0, stream>>>(ca, mask, lens);

    qkv_kernel<<<dim3(32, 8, 3), 256, 0, stream>>>(qbf, kbf, vbf, wqb, wkb, wvb,
                                                   bq, bk, bv, Qhb, Khb, Vtb);
    attn_kernel<<<dim3(512, 1), 256, 0, stream>>>(Qhb, Khb, Vtb, attb, lens);
    outproj_kernel<<<dim3(32, 8), 256, 0, stream>>>(attb, wob, bo, out);
}

// Round 5
// 223.296 us; speedup vs baseline: 1.0534x; 1.0072x over previous
//
#include <hip/hip_runtime.h>
#include <stdint.h>

#define D_MODEL 1024
#define NHEAD 16
#define DK 64
#define BATCH 2
#define SEQ 2048
#define NROW 4096  // BATCH*SEQ

typedef __attribute__((ext_vector_type(8))) _Float16 f16x8;
typedef __attribute__((ext_vector_type(4))) float f32x4;

__device__ __forceinline__ uint16_t f2h(float x) {
    _Float16 h = (_Float16)x;
    union { _Float16 h; uint16_t u; } cv;
    cv.h = h;
    return cv.u;
}

__device__ __forceinline__ float fexp2(float x) {
#if __has_builtin(__builtin_amdgcn_exp2f)
    return __builtin_amdgcn_exp2f(x);
#else
    return exp2f(x);
#endif
}

// async global->LDS DMA, 16B per lane, LDS dst = wave-uniform base + lane*16
__device__ __forceinline__ void lds_dma16(const uint16_t* g, uint16_t* l) {
    __builtin_amdgcn_global_load_lds((const __attribute__((address_space(1))) void*)g,
                                     (__attribute__((address_space(3))) void*)l,
                                     16, 0, 0);
}

// ---------- merged f32->f16 conversion (y=0..6) + mask->lens (y=7) ----------
struct CvtArgs {
    const float* src[7];
    uint16_t* dst[7];
    int n4[7];
};
__global__ void cvt_all_kernel(CvtArgs a, const int* __restrict__ mask, int* __restrict__ lens) {
    int t = blockIdx.y;
    if (t == 7) {
        if (blockIdx.x != 0) return;
        __shared__ int red[256];
        int tid = threadIdx.x;
        int mx = 0;
        for (int i = tid; i < 1024; i += 256) { int v = mask[i]; if (v > mx) mx = v; }
        red[tid] = mx; __syncthreads();
        for (int s = 128; s > 0; s >>= 1) { if (tid < s) { if (red[tid+s] > red[tid]) red[tid] = red[tid+s]; } __syncthreads(); }
        int bytemode = (red[0] > 1);
        __syncthreads();
        const unsigned char* mb = (const unsigned char*)mask;
        for (int b = 0; b < BATCH; ++b) {
            int cnt = 0;
            for (int tt = tid; tt < SEQ; tt += 256) {
                int v = bytemode ? (int)mb[b*SEQ + tt] : mask[b*SEQ + tt];
                cnt += (v != 0) ? 1 : 0;
            }
            red[tid] = cnt; __syncthreads();
            for (int s = 128; s > 0; s >>= 1) { if (tid < s) red[tid] += red[tid+s]; __syncthreads(); }
            if (tid == 0) lens[b] = red[0];
            __syncthreads();
        }
        return;
    }
    const float* src = a.src[t];
    uint16_t* dst = a.dst[t];
    int n4 = a.n4[t];
    int i = blockIdx.x * blockDim.x + threadIdx.x;
    int stride = gridDim.x * blockDim.x;
    for (; i < n4; i += stride) {
        float4 v = ((const float4*)src)[i];
        ushort4 o;
        o.x = f2h(v.x); o.y = f2h(v.y); o.z = f2h(v.z); o.w = f2h(v.w);
        ((ushort4*)dst)[i] = o;
    }
}

// ---------- 128x128 NT GEMM core, BK=64, global_load_lds + XOR-swizzled LDS ----------
__device__ __forceinline__ void gemm_tile_core(const uint16_t* __restrict__ A,
                                               const uint16_t* __restrict__ W,
                                               int bx, int by,
                                               uint16_t* As, uint16_t* Bs,
                                               f32x4 (&acc)[4][4]) {
    const f32x4 fzero = {0.f, 0.f, 0.f, 0.f};
    int tid = threadIdx.x;
    int lane = tid & 63, wave = tid >> 6;
    int wm = wave >> 1, wn = wave & 1;
    int l15 = lane & 15, quad = lane >> 4;
    int rl = lane >> 3, cb8 = lane & 7;  // DMA: 1KB chunk = 8 rows x 128B
#pragma unroll
    for (int mi = 0; mi < 4; mi++)
#pragma unroll
        for (int ni = 0; ni < 4; ni++) acc[mi][ni] = fzero;

    for (int k0 = 0; k0 < D_MODEL; k0 += 64) {
        __syncthreads();
#pragma unroll
        for (int i = 0; i < 4; ++i) {
            int d8 = wave * 4 + i;
            int row = d8 * 8 + rl;
            int cbg = cb8 ^ rl;
            lds_dma16(A + (size_t)(bx * 128 + row) * D_MODEL + k0 + cbg * 8, As + d8 * 512);
            lds_dma16(W + (size_t)(by * 128 + row) * D_MODEL + k0 + cbg * 8, Bs + d8 * 512);
        }
        __syncthreads();
#pragma unroll
        for (int ks = 0; ks < 2; ks++) {
            f16x8 af[4], bf[4];
#pragma unroll
            for (int mi = 0; mi < 4; mi++) {
                int row = wm * 64 + mi * 16 + l15;
                af[mi] = *(const f16x8*)(As + row * 64 + (((ks * 4 + quad) ^ (row & 7)) * 8));
            }
#pragma unroll
            for (int ni = 0; ni < 4; ni++) {
                int row = wn * 64 + ni * 16 + l15;
                bf[ni] = *(const f16x8*)(Bs + row * 64 + (((ks * 4 + quad) ^ (row & 7)) * 8));
            }
#pragma unroll
            for (int mi = 0; mi < 4; mi++)
#pragma unroll
                for (int ni = 0; ni < 4; ni++)
                    acc[mi][ni] = __builtin_amdgcn_mfma_f32_16x16x32_f16(af[mi], bf[ni], acc[mi][ni], 0, 0, 0);
        }
    }
}

// ---------- QKV projection; V goes through LDS transpose (aliased) ----------
#define TS_STRIDE 136  // u16; 272B rows -> 16B aligned, odd-word bank spread
__global__ __launch_bounds__(256, 3) void qkv_kernel(
    const uint16_t* __restrict__ qb, const uint16_t* __restrict__ kb, const uint16_t* __restrict__ vb,
    const uint16_t* __restrict__ wq, const uint16_t* __restrict__ wk, const uint16_t* __restrict__ wv,
    const float* __restrict__ bq, const float* __restrict__ bk, const float* __restrict__ bv,
    uint16_t* __restrict__ Qh, uint16_t* __restrict__ Kh, uint16_t* __restrict__ Vth) {
    __shared__ uint16_t smem[TS_STRIDE * 128];  // 34816B >= As+Bs (32KB) or Ts
    uint16_t* As = smem;
    uint16_t* Bs = smem + 128 * 64;
    int v = blockIdx.z;
    const uint16_t* A = (v == 0) ? qb : ((v == 1) ? kb : vb);
    const uint16_t* W = (v == 0) ? wq : ((v == 1) ? wk : wv);
    const float* bias = (v == 0) ? bq : ((v == 1) ? bk : bv);
    f32x4 acc[4][4];
    gemm_tile_core(A, W, blockIdx.x, blockIdx.y, As, Bs, acc);

    int tid = threadIdx.x, lane = tid & 63, wave = tid >> 6;
    int wm = wave >> 1, wn = wave & 1, l15 = lane & 15, quad = lane >> 4;
    // Q pre-scale folds 1/sqrt(dk) AND log2(e) so attention uses raw exp2.
    const float QSCALE = 0.125f * 1.44269504088896f;

    if (v == 2) {
        __syncthreads();  // all waves done reading As/Bs before aliasing as Ts
        uint16_t* Ts = smem;
#pragma unroll
        for (int mi = 0; mi < 4; mi++) {
#pragma unroll
            for (int ni = 0; ni < 4; ni++) {
                int col = wn * 64 + ni * 16 + l15;
                float bcol = bias[blockIdx.y * 128 + col];
#pragma unroll
                for (int r = 0; r < 4; r++) {
                    int tl = wm * 64 + mi * 16 + quad * 4 + r;
                    Ts[col * TS_STRIDE + tl] = f2h(acc[mi][ni][r] + bcol);
                }
            }
        }
        __syncthreads();
        int col = tid >> 1, th = (tid & 1) << 6;
        int gcol = blockIdx.y * 128 + col;
        int h = gcol >> 6, d = gcol & 63;
        int grow0 = blockIdx.x * 128;
        int b = grow0 >> 11, t = (grow0 & (SEQ - 1)) + th;
        size_t base = (((size_t)(b * NHEAD + h) << 6) + d) * SEQ + t;
#pragma unroll
        for (int j = 0; j < 8; j++)
            *(uint4*)(Vth + base + j * 8) = *(const uint4*)(Ts + col * TS_STRIDE + th + j * 8);
        return;
    }

#pragma unroll
    for (int mi = 0; mi < 4; mi++) {
#pragma unroll
        for (int ni = 0; ni < 4; ni++) {
            int gcol = blockIdx.y * 128 + wn * 64 + ni * 16 + l15;
            float bcol = bias[gcol];
            int h = gcol >> 6, d = gcol & 63;
#pragma unroll
            for (int r = 0; r < 4; r++) {
                int grow = blockIdx.x * 128 + wm * 64 + mi * 16 + quad * 4 + r;
                int b = grow >> 11, t = grow & (SEQ - 1);
                float val = acc[mi][ni][r] + bcol;
                size_t bh = (size_t)(b * NHEAD + h);
                if (v == 0) Qh[(bh * SEQ + t) * 64 + d] = f2h(val * QSCALE);
                else        Kh[(bh * SEQ + t) * 64 + d] = f2h(val);
            }
        }
    }
}

// ---------- output projection ----------
__global__ __launch_bounds__(256, 3) void outproj_kernel(
    const uint16_t* __restrict__ attn, const uint16_t* __restrict__ wo,
    const float* __restrict__ bo, float* __restrict__ out) {
    __shared__ uint16_t As[128 * 64], Bs[128 * 64];
    f32x4 acc[4][4];
    gemm_tile_core(attn, wo, blockIdx.x, blockIdx.y, As, Bs, acc);
    int tid = threadIdx.x, lane = tid & 63, wave = tid >> 6;
    int wm = wave >> 1, wn = wave & 1, l15 = lane & 15, quad = lane >> 4;
#pragma unroll
    for (int mi = 0; mi < 4; mi++) {
#pragma unroll
        for (int ni = 0; ni < 4; ni++) {
            int gcol = blockIdx.y * 128 + wn * 64 + ni * 16 + l15;
            float bcol = bo[gcol];
#pragma unroll
            for (int r = 0; r < 4; r++) {
                int grow = blockIdx.x * 128 + wm * 64 + mi * 16 + quad * 4 + r;
                out[(size_t)grow * D_MODEL + gcol] = acc[mi][ni][r] + bcol;
            }
        }
    }
}

// ---------- flash attention v13: deferred-PV software pipeline ----------
// Base = v10 (46us proven): R4 layout, depth-2 K prefetch, partial-drain vmcnt(2)
// barriers, XCD-affine bh map, NO setprio (v12 A/B: setprio = -7%, reverted).
// v13 single structural change: iteration kt computes
//     QK(kt) -> PV(kt-1) -> softmax(kt)->P[kt&1]
// instead of QK->softmax->PV on the same tile. Effects:
//   - kills the per-tile P LDS write->immediate-read lgkm turnaround (~150-250cy
//     per wave): P is double-buffered, read one iter after write, covered by work.
//   - QK(kt) and PV(kt-1) are data-independent -> 18 MFMA issue back-to-back,
//     interleavable with kf ds_read latency by the compiler.
// Requires V triple-buffer (PV reads V(kt-1) while V(kt+1) streams in): LDS 64KB,
// still 2 blocks/CU (grid mandates 2 anyway). DMA issue order and the vmcnt(2)
// invariant are BYTE-IDENTICAL to v10 (V(kt+1),K(kt+2) per iter; retire 4 oldest).
#define PIPE_WAIT2_BARRIER() do { asm volatile("s_waitcnt vmcnt(2)" ::: "memory"); __builtin_amdgcn_s_barrier(); } while (0)
#define PIPE_WAIT0_BARRIER() do { asm volatile("s_waitcnt vmcnt(0)" ::: "memory"); __builtin_amdgcn_s_barrier(); } while (0)

__device__ __forceinline__ void flash_item(
    int qt, int bh, int b, int h, int L,
    const uint16_t* __restrict__ Qh, const uint16_t* __restrict__ Kh, const uint16_t* __restrict__ Vth,
    uint16_t* __restrict__ attn,
    uint16_t* KtA, uint16_t* VtA, uint16_t* Ptw) {
    const f32x4 fzero = {0.f, 0.f, 0.f, 0.f};
    const float MFIX = 6.0f;
    int tid = threadIdx.x, lane = tid & 63, w = tid >> 6;
    int l15 = lane & 15, quad = lane >> 4, l7 = l15 & 7;
    int q0 = qt * 64;
    int rl = lane >> 3, cb8 = lane & 7;

    f16x8 ones;
#pragma unroll
    for (int j = 0; j < 8; j++) ones[j] = (_Float16)1.0f;

    f16x8 qf[2];
#pragma unroll
    for (int ks = 0; ks < 2; ks++)
        qf[ks] = *(const f16x8*)(Qh + ((size_t)bh * SEQ + q0 + w * 16 + l15) * 64 + ks * 32 + quad * 8);

    f32x4 o_acc[4], l_acc = fzero;
#pragma unroll
    for (int ni = 0; ni < 4; ni++) o_acc[ni] = fzero;

    int nkt_p = (L + 63) >> 6;
    int nkt = (qt + 1 < nkt_p) ? (qt + 1) : nkt_p;

    const uint16_t* Kbh = Kh + (size_t)bh * SEQ * 64;
    const uint16_t* Vbh = Vth + ((size_t)bh << 6) * SEQ;

    auto stageK = [&](int kt_, int slot) {
#pragma unroll
        for (int i_ = 0; i_ < 2; ++i_) {
            int d8 = w * 2 + i_;
            int row = d8 * 8 + rl;
            int cbg = cb8 ^ rl;
            lds_dma16(Kbh + (size_t)(kt_ * 64 + row) * 64 + cbg * 8, KtA + slot * 4096 + d8 * 512);
        }
    };
    auto stageV = [&](int kt_, int slot) {
#pragma unroll
        for (int i_ = 0; i_ < 2; ++i_) {
            int d8 = w * 2 + i_;
            int row = d8 * 8 + rl;
            int cbg = cb8 ^ rl;
            lds_dma16(Vbh + (size_t)row * SEQ + kt_ * 64 + cbg * 8, VtA + slot * 4096 + d8 * 512);
        }
    };

    // PV helper for tile kt_ (reads P buffer (kt_&1), V slot (kt_%3))
    auto pv_tile = [&](int kt_) {
        const uint16_t* Vp = VtA + (kt_ % 3) * 4096;
        const uint16_t* Pp = Ptw + (kt_ & 1) * 1024;
#pragma unroll
        for (int ks = 0; ks < 2; ks++) {
            f16x8 pa = *(const f16x8*)(Pp + l15 * 64 + (((ks * 4 + quad) ^ l7) * 8));
            l_acc = __builtin_amdgcn_mfma_f32_16x16x32_f16(pa, ones, l_acc, 0, 0, 0);
            f16x8 vbf[4];
#pragma unroll
            for (int ni = 0; ni < 4; ni++) {
                int row = ni * 16 + l15;
                vbf[ni] = *(const f16x8*)(Vp + row * 64 + (((ks * 4 + quad) ^ (row & 7)) * 8));
            }
#pragma unroll
            for (int ni = 0; ni < 4; ni++)
                o_acc[ni] = __builtin_amdgcn_mfma_f32_16x16x32_f16(pa, vbf[ni], o_acc[ni], 0, 0, 0);
        }
    };

    // prologue: V0,K0 drained; K1 left in flight (steady-state invariant)
    stageV(0, 0);
    stageK(0, 0);
    PIPE_WAIT0_BARRIER();
    stageK((1 < nkt) ? 1 : 0, 1);

    int kcur = 0;
    for (int kt = 0; kt < nkt; ++kt) {
        int ktV = (kt + 1 < nkt) ? kt + 1 : nkt - 1;
        int ktK = (kt + 2 < nkt) ? kt + 2 : nkt - 1;
        stageV(ktV, (kt + 1) % 3);            // issued FIRST: retired by vmcnt(2) below
        int ks2 = (kcur >= 1) ? kcur - 1 : 2; // (kcur+2)%3
        stageK(ktK, ks2);

        const uint16_t* Kc = KtA + kcur * 4096;

        // ---- QK(kt): S = Q K^T (log2-domain; scale folded into Q) ----
        f32x4 s_acc[4];
#pragma unroll
        for (int ni = 0; ni < 4; ni++) s_acc[ni] = fzero;
#pragma unroll
        for (int ks = 0; ks < 2; ks++) {
            f16x8 kf[4];
#pragma unroll
            for (int ni = 0; ni < 4; ni++) {
                int row = ni * 16 + l15;
                kf[ni] = *(const f16x8*)(Kc + row * 64 + (((ks * 4 + quad) ^ (row & 7)) * 8));
            }
#pragma unroll
            for (int ni = 0; ni < 4; ni++)
                s_acc[ni] = __builtin_amdgcn_mfma_f32_16x16x32_f16(qf[ks], kf[ni], s_acc[ni], 0, 0, 0);
        }

        // ---- PV(kt-1): independent of QK(kt); P read from other buffer ----
        if (kt > 0) pv_tile(kt - 1);

        // ---- softmax(kt): p = exp2(s - MFIX) -> P buffer (kt&1) ----
        {
            uint16_t* Pw = Ptw + (kt & 1) * 1024;
            bool full = (kt < qt) && (kt * 64 + 64 <= L);
#pragma unroll
            for (int r = 0; r < 4; r++) {
                int prow = quad * 4 + r;
                int q_idx = q0 + w * 16 + prow;
                int pr7 = prow & 7;
#pragma unroll
                for (int ni = 0; ni < 4; ni++) {
                    float s = s_acc[ni][r];
                    if (!full) {
                        int key = kt * 64 + ni * 16 + l15;
                        s = ((key <= q_idx) && (key < L)) ? s : -1e9f;
                    }
                    float p = fexp2(s - MFIX);
                    int cb = ni * 2 + (l15 >> 3);
                    Pw[prow * 64 + ((cb ^ pr7) * 8) + l7] = f2h(p);
                }
            }
        }

        PIPE_WAIT2_BARRIER();
        kcur = (kcur == 2) ? 0 : kcur + 1;
    }

    // ---- drain: PV(nkt-1); V slot (nkt-1)%3 untouched by tail dummy stages ----
    __asm__ __volatile__("" ::: "memory");  // order last P stores vs loads
    pv_tile(nkt - 1);

    // ---- epilogue: O / l ----
#pragma unroll
    for (int r = 0; r < 4; r++) {
        float inv = 1.0f / l_acc[r];
        int q_idx = q0 + w * 16 + quad * 4 + r;
#pragma unroll
        for (int ni = 0; ni < 4; ni++) {
            attn[((size_t)(b * SEQ + q_idx)) * D_MODEL + h * 64 + ni * 16 + l15] =
                f2h(o_acc[ni][r] * inv);
        }
    }
}

__global__ __launch_bounds__(256, 2) void attn_kernel(
    const uint16_t* __restrict__ Qh, const uint16_t* __restrict__ Kh, const uint16_t* __restrict__ Vth,
    uint16_t* __restrict__ attn, const int* __restrict__ lens) {
    __shared__ uint16_t Kt[3 * 4096];  // 24KB: K tiles, prefetch distance 2
    __shared__ uint16_t Vt[3 * 4096];  // 24KB: V tiles, triple-buffer (deferred PV)
    __shared__ uint16_t Pt[8 * 1024];  // 16KB: wave-private P strips, double-buffered
    // v10 XCD-affine decode: XCD = n%8 (HW round-robin). Each XCD gets 4 heads,
    // all 16 q-tile blocks of a head on one XCD -> K/V L2-resident (2MB/XCD).
    // j = head slot 0..31; bh = (j&1)*16 + (j>>1) interleaves batches per XCD.
    int n = (int)blockIdx.x;
    int xcd = n & 7;
    int i = n >> 3;                     // 0..63
    int j = (xcd << 2) | (i & 3);       // 0..31
    int bh = ((j & 1) << 4) | (j >> 1); // bijective: 2 heads each batch per XCD
    int x = i >> 2;                     // 0..15
    int b = bh >> 4, h = bh & 15;
    int L = lens[b];
    int w = threadIdx.x >> 6;
    uint16_t* Ptw = Pt + w * 2048;      // 2 buffers x 1024 per wave
    // deterministic balance: pair (31-x, x) => 33 kt-tiles per block
    flash_item(31 - x, bh, b, h, L, Qh, Kh, Vth, attn, Kt, Vt, Ptw);
    flash_item(x, bh, b, h, L, Qh, Kh, Vth, attn, Kt, Vt, Ptw);
}

extern "C" void kernel_launch(void* const* d_in, const int* in_sizes, int n_in,
                              void* d_out, int out_size, void* d_ws, size_t ws_size,
                              hipStream_t stream) {
    const float* q  = (const float*)d_in[0];
    const float* k  = (const float*)d_in[1];
    const float* v  = (const float*)d_in[2];
    const int*   mask = (const int*)d_in[3];
    const float* Wq = (const float*)d_in[4];
    const float* bq = (const float*)d_in[5];
    const float* Wk = (const float*)d_in[6];
    const float* bk = (const float*)d_in[7];
    const float* Wv = (const float*)d_in[8];
    const float* bv = (const float*)d_in[9];
    const float* Wo = (const float*)d_in[10];
    const float* bo = (const float*)d_in[11];
    float* out = (float*)d_out;

    char* ws = (char*)d_ws;
    size_t off = 0;
    auto alloc = [&](size_t bytes) -> char* {
        char* p = ws + off;
        off += (bytes + 255) & ~(size_t)255;
        return p;
    };
    const size_t inp_e = (size_t)NROW * D_MODEL;
    const size_t w_e   = (size_t)D_MODEL * D_MODEL;
    uint16_t* qbf  = (uint16_t*)alloc(inp_e * 2);
    uint16_t* kbf  = (uint16_t*)alloc(inp_e * 2);
    uint16_t* vbf  = (uint16_t*)alloc(inp_e * 2);
    uint16_t* wqb  = (uint16_t*)alloc(w_e * 2);
    uint16_t* wkb  = (uint16_t*)alloc(w_e * 2);
    uint16_t* wvb  = (uint16_t*)alloc(w_e * 2);
    uint16_t* wob  = (uint16_t*)alloc(w_e * 2);
    uint16_t* Qhb  = (uint16_t*)alloc(inp_e * 2);
    uint16_t* Khb  = (uint16_t*)alloc(inp_e * 2);
    uint16_t* Vtb  = (uint16_t*)alloc(inp_e * 2);
    uint16_t* attb = (uint16_t*)alloc(inp_e * 2);
    int* lens      = (int*)alloc(256);

    CvtArgs ca;
    ca.src[0] = q;  ca.dst[0] = qbf; ca.n4[0] = (int)(inp_e / 4);
    ca.src[1] = k;  ca.dst[1] = kbf; ca.n4[1] = (int)(inp_e / 4);
    ca.src[2] = v;  ca.dst[2] = vbf; ca.n4[2] = (int)(inp_e / 4);
    ca.src[3] = Wq; ca.dst[3] = wqb; ca.n4[3] = (int)(w_e / 4);
    ca.src[4] = Wk; ca.dst[4] = wkb; ca.n4[4] = (int)(w_e / 4);
    ca.src[5] = Wv; ca.dst[5] = wvb; ca.n4[5] = (int)(w_e / 4);
    ca.src[6] = Wo; ca.dst[6] = wob; ca.n4[6] = (int)(w_e / 4);
    cvt_all_kernel<<<dim3(128, 8), 256, 0, stream>>>(ca, mask, lens);

    qkv_kernel<<<dim3(32, 8, 3), 256, 0, stream>>>(qbf, kbf, vbf, wqb, wkb, wvb,
                                                   bq, bk, bv, Qhb, Khb, Vtb);
    attn_kernel<<<dim3(512, 1), 256, 0, stream>>>(Qhb, Khb, Vtb, attb, lens);
    outproj_kernel<<<dim3(32, 8), 256, 0, stream>>>(attb, wob, bo, out);
}